// Round 5
// baseline (414.705 us; speedup 1.0000x reference)
//
#include <hip/hip_runtime.h>

// KNN top-16: B=4, N=8192, D=16, k=16, fp32 in, int32 index out.
// FROZEN key model (validated R11-R23, absmax=0): harness np twin =
//   dot  = BLAS microkernel single-accumulator FMA chain, k = 0..15
//   norm = numpy AVX512 pairwise tree: r_j=m_j+m_{j+8}; q_j=r_j+r_{j+4};
//          fl(fl(q0+q2)+fl(q1+q3))
//   val  = fl( fl(ni + fl(-2*dot)) + nj ), ties -> lower index
//   pk_* VOP3P per-half == scalar IEEE (validated R23, absmax=0)
// Keys packed u64 = (mono32(key)<<32)|idx: u64 asc == (key asc, idx asc).
// R24: query-blocking Q=2. R23 post-mortem: VALU slots -25% (VALUBusy
// 86->65) with dur FLAT -> not VALU-bound. Bottleneck = LDS read pipe:
// 8x ds_read_b128/pair, wave-uniform broadcast still costs ~12cyc/instr
// (return path is per-lane: 1024B/instr at 85B/cyc), 16 waves/CU x 512
// pairs x 96cyc = 786K cyc/CU = 328us ~= measured. 64x broadcast waste.
// Fix: each lane owns 2 queries (lane -> blk*128+lane, +64); each LDS
// read amortizes over 128 queries/wave -> LDS/interaction halves. Grid
// 256 blocks = 1/CU; LDS now free: dual CAP-12 pbufs (96KB), total
// 104.5KB. Merge = 4 passes x 32 queries (32KB overlay). (BT_,1) ->
// VGPR cap 256 (need ~180-200). Predict: dur 366->200-240 profiled,
// Occupancy ~25 (benign), WRITE_SIZE ~2MB (else spill -> revert).

#define B_    4
#define N_    8192
#define D_    16
#define K_    16
#define SEGS_ 8
#define SEG_  (N_ / SEGS_)   // 1024
#define CH_   8              // rows per staged chunk
#define NCH_  (SEG_ / CH_)   // 128 chunks
#define BT_   512            // 8 waves
#define CAP_  12             // per-lane per-query LDS push-buffer capacity
#define NQ_   (B_ * N_)      // 32768 queries
#define QB_   128            // queries per block (2 per lane)

typedef unsigned long long u64;
typedef float v2f __attribute__((ext_vector_type(2)));

// VOP3P packed fp32: one issue slot, two IEEE fp32 ops (per-half == scalar)
__device__ __forceinline__ v2f pk_fma(v2f a, v2f b, v2f c) {
  v2f d;
  asm("v_pk_fma_f32 %0, %1, %2, %3" : "=v"(d) : "v"(a), "v"(b), "v"(c));
  return d;
}
__device__ __forceinline__ v2f pk_mul(v2f a, v2f b) {
  v2f d;
  asm("v_pk_mul_f32 %0, %1, %2" : "=v"(d) : "v"(a), "v"(b));
  return d;
}
__device__ __forceinline__ v2f pk_add(v2f a, v2f b) {
  v2f d;
  asm("v_pk_add_f32 %0, %1, %2" : "=v"(d) : "v"(a), "v"(b));
  return d;
}

// numpy AVX512 pairwise-sum tree for 16 contiguous floats. FROZEN.
__device__ __forceinline__ float np_norm16(const float* __restrict__ p) {
#pragma clang fp contract(off)
  float m[16];
#pragma unroll
  for (int d = 0; d < 16; ++d) m[d] = p[d] * p[d];
  float r[8];
#pragma unroll
  for (int j = 0; j < 8; ++j) r[j] = m[j] + m[j + 8];
  float q[4];
#pragma unroll
  for (int j = 0; j < 4; ++j) q[j] = r[j] + r[j + 4];
  return (q[0] + q[2]) + (q[1] + q[3]);
}

// monotone fp32->u32: uint ascending == float ascending (handles negatives)
__device__ __forceinline__ unsigned mono32(float f) {
  unsigned u = __float_as_uint(f);
  return u ^ ((unsigned)((int)u >> 31) | 0x80000000u);
}

__global__ __launch_bounds__(256) void knn_norms(const float* __restrict__ x,
                                                 float* __restrict__ nrm) {
  int q = blockIdx.x * 256 + threadIdx.x;
  float row[16];
  const float4* xv = (const float4*)(x + (size_t)q * D_);
  float4 a = xv[0], b = xv[1], c = xv[2], d = xv[3];
  row[0]=a.x; row[1]=a.y; row[2]=a.z; row[3]=a.w;
  row[4]=b.x; row[5]=b.y; row[6]=b.z; row[7]=b.w;
  row[8]=c.x; row[9]=c.y; row[10]=c.z; row[11]=c.w;
  row[12]=d.x; row[13]=d.y; row[14]=d.z; row[15]=d.w;
  nrm[q] = np_norm16(row);
}

// ascending insert; '>' keeps earlier (lower idx) on ties
__device__ __forceinline__ void insert16(float d, int j, float (&kd)[K_], int (&ki)[K_]) {
  float cd = d; int ci = j;
#pragma unroll
  for (int p = 0; p < K_; ++p) {
    bool gt = kd[p] > cd;
    float t0 = gt ? cd : kd[p];
    float t1 = gt ? kd[p] : cd;
    int   t2 = gt ? ci : ki[p];
    int   t3 = gt ? ki[p] : ci;
    kd[p] = t0; cd = t1; ki[p] = t2; ci = t3;
  }
}

__device__ __forceinline__ void flushbuf(u64* __restrict__ pbuf, int tid,
                                         int& count, float& thr,
                                         float (&kd)[K_], int (&ki)[K_]) {
#pragma unroll 1
  for (int s = 0; s < CAP_; ++s) {
    if (s < count) {
      u64 e = pbuf[s * BT_ + tid];
      float d = __uint_as_float((unsigned)(e >> 32));
      if (d < thr) {
        int j = (int)(e & 0xffffu);
        insert16(d, j, kd, ki);
        thr = kd[K_ - 1];
      }
    }
  }
  count = 0;
}

// publish 32 queries' heaps into overlay, 8-way tournament merge, write out
__device__ __forceinline__ void pub_merge(u64* __restrict__ mrg,
                                          const float (&kd)[K_], const int (&ki)[K_],
                                          int w, int lane, int tid, int hl,
                                          int qbase, int* __restrict__ out) {
  if ((lane >> 5) == hl) {
    const int lm = lane & 31;
#pragma unroll
    for (int p = 0; p < K_; ++p) {
      mrg[((size_t)w * 16 + p) * 32 + lm] =
          ((u64)mono32(kd[p]) << 32) | (unsigned)(w * SEG_ + ki[p]);
    }
  }
  __syncthreads();
  if (tid < 256) {
    const int m = tid >> 3;                        // query-in-pass
    const int s = tid & 7;                         // segment stream
    int ptr = 0;
#pragma unroll 1
    for (int r = 0; r < K_; ++r) {
      u64 hd = mrg[((size_t)s * 16 + ptr) * 32 + m];
      u64 mv = hd, o;
      o = __shfl_xor(mv, 1); mv = (o < mv) ? o : mv;
      o = __shfl_xor(mv, 2); mv = (o < mv) ? o : mv;
      o = __shfl_xor(mv, 4); mv = (o < mv) ? o : mv;
      if (hd == mv) ++ptr;                         // exactly one lane advances
      if (s == 0) out[(size_t)(qbase + m) * K_ + r] = (int)(mv & 0xffffu);
    }
  }
  __syncthreads();                                 // overlay reuse by next pass
}

__global__ __launch_bounds__(BT_, 1) void knn_fused(const float* __restrict__ x,
                                                    const float* __restrict__ nrm,
                                                    int* __restrict__ out) {
  __shared__ u64 smem[13376];                      // 104.5 KB (1 block/CU)
  v2f*    stageT = (v2f*)smem;                     // [(w*2+b)*64 + p*16+d], 8 KB
  float*  stageN = (float*)(smem + 1024);          // [(w*2+b)*8 + i], 512 B
  u64*    pbufA  = smem + 1088;                    // [s*512 + tid], 48 KB
  u64*    pbufB  = smem + 7232;                    // [s*512 + tid], 48 KB
  // merge overlay (after final flush): smem+1088, (8*16*32)*8 = 32 KB

  const int tid  = threadIdx.x;
  const int w    = tid >> 6;                       // wave id = segment
  const int lane = tid & 63;
  const int q0   = blockIdx.x * QB_ + lane;        // query A
  const int q1   = q0 + 64;                        // query B
  const int bq   = (int)((blockIdx.x * (unsigned)QB_) >> 13);  // batch
  const int row0 = bq * N_ + w * SEG_;
  const float* __restrict__ cbase = x + (size_t)row0 * D_;
  const float* __restrict__ nbase = nrm + row0;

  const int p_ = lane >> 4;                        // staging pair slot 0..3
  const int d_ = lane & 15;                        // staging dim 0..15

  // packed queries: qqX[d] = (qaX[d], qaX[d])
  v2f qqA[D_], qqB[D_];
  {
    const float4* qv = (const float4*)(x + (size_t)q0 * D_);
    float4 v0 = qv[0], v1 = qv[1], v2 = qv[2], v3 = qv[3];
    qqA[0]=(v2f){v0.x,v0.x}; qqA[1]=(v2f){v0.y,v0.y}; qqA[2]=(v2f){v0.z,v0.z}; qqA[3]=(v2f){v0.w,v0.w};
    qqA[4]=(v2f){v1.x,v1.x}; qqA[5]=(v2f){v1.y,v1.y}; qqA[6]=(v2f){v1.z,v1.z}; qqA[7]=(v2f){v1.w,v1.w};
    qqA[8]=(v2f){v2.x,v2.x}; qqA[9]=(v2f){v2.y,v2.y}; qqA[10]=(v2f){v2.z,v2.z}; qqA[11]=(v2f){v2.w,v2.w};
    qqA[12]=(v2f){v3.x,v3.x}; qqA[13]=(v2f){v3.y,v3.y}; qqA[14]=(v2f){v3.z,v3.z}; qqA[15]=(v2f){v3.w,v3.w};
  }
  {
    const float4* qv = (const float4*)(x + (size_t)q1 * D_);
    float4 v0 = qv[0], v1 = qv[1], v2 = qv[2], v3 = qv[3];
    qqB[0]=(v2f){v0.x,v0.x}; qqB[1]=(v2f){v0.y,v0.y}; qqB[2]=(v2f){v0.z,v0.z}; qqB[3]=(v2f){v0.w,v0.w};
    qqB[4]=(v2f){v1.x,v1.x}; qqB[5]=(v2f){v1.y,v1.y}; qqB[6]=(v2f){v1.z,v1.z}; qqB[7]=(v2f){v1.w,v1.w};
    qqB[8]=(v2f){v2.x,v2.x}; qqB[9]=(v2f){v2.y,v2.y}; qqB[10]=(v2f){v2.z,v2.z}; qqB[11]=(v2f){v2.w,v2.w};
    qqB[12]=(v2f){v3.x,v3.x}; qqB[13]=(v2f){v3.y,v3.y}; qqB[14]=(v2f){v3.z,v3.z}; qqB[15]=(v2f){v3.w,v3.w};
  }
  const float niA = nrm[q0], niB = nrm[q1];
  const v2f nipA = (v2f){niA, niA};
  const v2f nipB = (v2f){niB, niB};
  const v2f m2   = (v2f){-2.0f, -2.0f};

  float kdA[K_], kdB[K_]; int kiA[K_], kiB[K_];
#pragma unroll
  for (int p = 0; p < K_; ++p) {
    kdA[p] = 3.4e38f; kiA[p] = 0;
    kdB[p] = 3.4e38f; kiB[p] = 0;
  }
  float thrA = 3.4e38f, thrB = 3.4e38f;
  int cntA = 0, cntB = 0;

  // stage chunk 0 pair-transposed (per-wave-private LDS; wave-synchronous)
  {
    float g0 = cbase[(2 * p_) * D_ + d_];
    float g1 = cbase[(2 * p_ + 1) * D_ + d_];
    stageT[(w * 2 + 0) * 64 + p_ * 16 + d_] = (v2f){g0, g1};
    if (lane < CH_) stageN[(w * 2 + 0) * CH_ + lane] = nbase[lane];
  }

#pragma unroll 1
  for (int c = 0; c < NCH_; ++c) {
    const int b = c & 1;
    // prefetch chunk c+1 into registers (overlaps compute below)
    float pg0 = 0.f, pg1 = 0.f, pn = 0.f;
    const bool more = (c + 1 < NCH_);
    if (more) {
      const float* cb = cbase + (size_t)(c + 1) * CH_ * D_;
      pg0 = cb[(2 * p_) * D_ + d_];
      pg1 = cb[(2 * p_ + 1) * D_ + d_];
      if (lane < CH_) pn = nbase[(c + 1) * CH_ + lane];
    }

    const float4* tp = (const float4*)(stageT + (w * 2 + b) * 64);
    const float*  nW = stageN + (w * 2 + b) * CH_;
    const int j0 = c * CH_;

#pragma unroll 1
    for (int p = 0; p < 4; ++p) {
      // 8 wave-uniform b128 reads: f_i = (c0[2i], c1[2i], c0[2i+1], c1[2i+1])
      float4 f0 = tp[p*8+0], f1 = tp[p*8+1], f2 = tp[p*8+2], f3 = tp[p*8+3];
      float4 f4 = tp[p*8+4], f5 = tp[p*8+5], f6 = tp[p*8+6], f7 = tp[p*8+7];

      // frozen single-accumulator chains; lo=cand0 / hi=cand1; A,B interleaved
      v2f accA = (v2f){0.f, 0.f}, accB = (v2f){0.f, 0.f};
      accA = pk_fma(qqA[0],  (v2f){f0.x, f0.y}, accA);
      accB = pk_fma(qqB[0],  (v2f){f0.x, f0.y}, accB);
      accA = pk_fma(qqA[1],  (v2f){f0.z, f0.w}, accA);
      accB = pk_fma(qqB[1],  (v2f){f0.z, f0.w}, accB);
      accA = pk_fma(qqA[2],  (v2f){f1.x, f1.y}, accA);
      accB = pk_fma(qqB[2],  (v2f){f1.x, f1.y}, accB);
      accA = pk_fma(qqA[3],  (v2f){f1.z, f1.w}, accA);
      accB = pk_fma(qqB[3],  (v2f){f1.z, f1.w}, accB);
      accA = pk_fma(qqA[4],  (v2f){f2.x, f2.y}, accA);
      accB = pk_fma(qqB[4],  (v2f){f2.x, f2.y}, accB);
      accA = pk_fma(qqA[5],  (v2f){f2.z, f2.w}, accA);
      accB = pk_fma(qqB[5],  (v2f){f2.z, f2.w}, accB);
      accA = pk_fma(qqA[6],  (v2f){f3.x, f3.y}, accA);
      accB = pk_fma(qqB[6],  (v2f){f3.x, f3.y}, accB);
      accA = pk_fma(qqA[7],  (v2f){f3.z, f3.w}, accA);
      accB = pk_fma(qqB[7],  (v2f){f3.z, f3.w}, accB);
      accA = pk_fma(qqA[8],  (v2f){f4.x, f4.y}, accA);
      accB = pk_fma(qqB[8],  (v2f){f4.x, f4.y}, accB);
      accA = pk_fma(qqA[9],  (v2f){f4.z, f4.w}, accA);
      accB = pk_fma(qqB[9],  (v2f){f4.z, f4.w}, accB);
      accA = pk_fma(qqA[10], (v2f){f5.x, f5.y}, accA);
      accB = pk_fma(qqB[10], (v2f){f5.x, f5.y}, accB);
      accA = pk_fma(qqA[11], (v2f){f5.z, f5.w}, accA);
      accB = pk_fma(qqB[11], (v2f){f5.z, f5.w}, accB);
      accA = pk_fma(qqA[12], (v2f){f6.x, f6.y}, accA);
      accB = pk_fma(qqB[12], (v2f){f6.x, f6.y}, accB);
      accA = pk_fma(qqA[13], (v2f){f6.z, f6.w}, accA);
      accB = pk_fma(qqB[13], (v2f){f6.z, f6.w}, accB);
      accA = pk_fma(qqA[14], (v2f){f7.x, f7.y}, accA);
      accB = pk_fma(qqB[14], (v2f){f7.x, f7.y}, accB);
      accA = pk_fma(qqA[15], (v2f){f7.z, f7.w}, accA);
      accB = pk_fma(qqB[15], (v2f){f7.z, f7.w}, accB);

      // val = fl( fl(ni + fl(-2*dot)) + nj ), per half (pk ops = scalar IEEE)
      v2f njp = *(const v2f*)(nW + 2 * p);
      v2f iA  = pk_mul(m2, accA);
      v2f iB  = pk_mul(m2, accB);
      v2f uA  = pk_add(nipA, iA);
      v2f uB  = pk_add(nipB, iB);
      v2f dA  = pk_add(uA, njp);
      v2f dB  = pk_add(uB, njp);
      const int j = j0 + 2 * p;

      if (dA.x < thrA) {
        pbufA[cntA * BT_ + tid] = ((u64)__float_as_uint(dA.x) << 32) | (unsigned)j;
        ++cntA;
      }
      if (dA.y < thrA) {
        pbufA[cntA * BT_ + tid] = ((u64)__float_as_uint(dA.y) << 32) | (unsigned)(j + 1);
        ++cntA;
      }
      if (dB.x < thrB) {
        pbufB[cntB * BT_ + tid] = ((u64)__float_as_uint(dB.x) << 32) | (unsigned)j;
        ++cntB;
      }
      if (dB.y < thrB) {
        pbufB[cntB * BT_ + tid] = ((u64)__float_as_uint(dB.y) << 32) | (unsigned)(j + 1);
        ++cntB;
      }
      if (__any(cntA >= CAP_ - 1)) flushbuf(pbufA, tid, cntA, thrA, kdA, kiA);
      if (__any(cntB >= CAP_ - 1)) flushbuf(pbufB, tid, cntB, thrB, kdB, kiB);
    }

    // write prefetched chunk into the other buffer (pair-transposed)
    if (more) {
      stageT[(w * 2 + (b ^ 1)) * 64 + p_ * 16 + d_] = (v2f){pg0, pg1};
      if (lane < CH_) stageN[(w * 2 + (b ^ 1)) * CH_ + lane] = pn;
    }
  }
  flushbuf(pbufA, tid, cntA, thrA, kdA, kiA);
  flushbuf(pbufB, tid, cntB, thrB, kdB, kiB);

  // ---- publish + 8-way merge, 4 passes of 32 queries (32 KB overlay) ----
  u64* mrg = smem + 1088;
  __syncthreads();   // all waves done with stage/push regions before overlay
  const int qb = blockIdx.x * QB_;
  pub_merge(mrg, kdA, kiA, w, lane, tid, 0, qb +  0, out);
  pub_merge(mrg, kdA, kiA, w, lane, tid, 1, qb + 32, out);
  pub_merge(mrg, kdB, kiB, w, lane, tid, 0, qb + 64, out);
  pub_merge(mrg, kdB, kiB, w, lane, tid, 1, qb + 96, out);
}

extern "C" void kernel_launch(void* const* d_in, const int* in_sizes, int n_in,
                              void* d_out, int out_size, void* d_ws, size_t ws_size,
                              hipStream_t stream) {
  const float* x = (const float*)d_in[0];
  float* nrm = (float*)d_ws;                       // 128 KB of workspace
  int* out = (int*)d_out;

  knn_norms<<<NQ_ / 256, 256, 0, stream>>>(x, nrm);
  knn_fused<<<NQ_ / QB_, BT_, 0, stream>>>(x, nrm, out);
}